// Round 15
// baseline (788.371 us; speedup 1.0000x reference)
//
#include <hip/hip_runtime.h>
#include <math.h>

#define IN_DIM 74
#define HID 128
#define LSEQ 1000
#define RSA 272      // 128-ch act LDS row bytes (17 x 16B)
#define RSB 208      // 96-ch act LDS row bytes (13 x 16B)
#define TILE 50
#define R0 58        // X0 rows, l = l0-4+r
#define R1 56        // X1 rows, l = l0-3+r
#define R2 54        // X2 rows, l = l0-2+r
#define R3 52        // X3 rows, l = l0-1+r
#define NCHUNK 42
#define NGRP 14
#define WBUF_SZ 24576
#define LDS_BIAS 49152
#define LDS_ACT  50944
#define ACTA_SZ  15776            // 58*272
#define ACTB_SZ  11648            // 56*208
#define ACTB_BASE (LDS_ACT + 4*ACTA_SZ)       // 114048
#define LDS_TOTAL (ACTB_BASE + 4*ACTB_SZ)     // 160640

typedef unsigned int u32;
typedef unsigned short u16;

typedef __attribute__((ext_vector_type(8))) short bf16x8;
typedef __attribute__((ext_vector_type(4))) float f32x4;

__device__ __forceinline__ u16 f2bf(float f){
  u32 u = __float_as_uint(f);
  u32 r = (u + 0x7fffu + ((u >> 16) & 1u)) >> 16;
  return (u16)r;
}
__device__ __forceinline__ u32 pack2(float x, float y){
  return (u32)f2bf(x) | ((u32)f2bf(y) << 16);
}

// ---------- graph branch ----------
__global__ void k_cnt_edge(const int* __restrict__ src, const int* __restrict__ dst,
                           int* out_cnt, int* in_cnt, int E){
  int e = blockIdx.x*256 + threadIdx.x;
  if (e < E){ atomicAdd(&out_cnt[src[e]], 1); atomicAdd(&in_cnt[dst[e]], 1); }
}
// nfs[i][f] = nf[i][f] * rsqrt(out_deg[i]+1)  (pre-scaled source rows)
__global__ void k_nfs(const float* __restrict__ nf, const int* __restrict__ out_cnt,
                      float* __restrict__ nfs, int total){
  int idx = blockIdx.x*256 + threadIdx.x;
  if (idx < total){
    int i = idx / IN_DIM;
    nfs[idx] = nf[idx] * rsqrtf((float)out_cnt[i] + 1.f);
  }
}
__global__ void k_scan1(const int* __restrict__ cnt, int* pref, int* bsum, int N){
  __shared__ int buf[256];
  int t = threadIdx.x, i = blockIdx.x*256 + t;
  int v = (i < N) ? cnt[i] : 0;
  buf[t] = v; __syncthreads();
  for (int o = 1; o < 256; o <<= 1){
    int tv = (t >= o) ? buf[t-o] : 0;
    __syncthreads(); buf[t] += tv; __syncthreads();
  }
  if (i < N) pref[i] = buf[t] - v;
  if (t == 255) bsum[blockIdx.x] = buf[255];
}
__global__ void k_scan2(int* bsum, int nb){
  __shared__ int buf[1024];
  int t = threadIdx.x;
  int v = (t < nb) ? bsum[t] : 0;
  buf[t] = v; __syncthreads();
  for (int o = 1; o < 1024; o <<= 1){
    int tv = (t >= o) ? buf[t-o] : 0;
    __syncthreads(); buf[t] += tv; __syncthreads();
  }
  if (t < nb) bsum[t] = buf[t] - v;
}
__global__ void k_scan3(const int* __restrict__ pref, const int* __restrict__ bsum,
                        int* offs, int* cur, int N){
  int i = blockIdx.x*256 + threadIdx.x;
  if (i < N){ int o = pref[i] + bsum[blockIdx.x]; offs[i] = o; cur[i] = o; }
}
__global__ void k_csr_fill(const int* __restrict__ src, const int* __restrict__ dst,
                           int* cur, int* csr_src, int E){
  int e = blockIdx.x*256 + threadIdx.x;
  if (e < E){ int slot = atomicAdd(&cur[dst[e]], 1); csr_src[slot] = src[e]; }
}

// fused: CSR gather (pre-scaled rows) + GraphConv GEMM + bias + ReLU + segment sum -> S
// 16 nodes per block: 2x gather TLP vs 32-node version.
__global__ __launch_bounds__(256) void k_mega(const float* __restrict__ nfs,
    const int* __restrict__ csr_src, const int* __restrict__ offs,
    const int* __restrict__ in_cnt,
    const float* __restrict__ W, const float* __restrict__ bias,
    const int* __restrict__ gid, float* __restrict__ S, int N){
  __shared__ float Wl[IN_DIM*HID];       // 37.9 KB
  __shared__ float rowsT[IN_DIM][20];    // 16 nodes + 4 pad (80B stride = 5 slots)
  __shared__ int lgid[16];
  const int tid = threadIdx.x;
  const int base = blockIdx.x * 16;
  for (int i = tid; i < IN_DIM*HID; i += 256) Wl[i] = W[i];
  if (tid < 16) lgid[tid] = (base + tid < N) ? gid[base + tid] : 0;

  int wid = tid >> 6, lane = tid & 63;
  for (int nn = wid; nn < 16; nn += 4){
    int d = base + nn;
    float a0 = 0.f, a1 = 0.f;
    if (d < N){
      int beg = offs[d], num = in_cnt[d];
      const float* row = nfs + (size_t)d*IN_DIM;
      a0 = row[lane];
      if (lane < IN_DIM-64) a1 = row[64+lane];
      int s = (num > 0) ? csr_src[beg] : 0;
      for (int j = 0; j < num; ++j){
        int snext = (j+1 < num) ? csr_src[beg+j+1] : 0;   // prefetch index
        const float* rs = nfs + (size_t)s*IN_DIM;
        a0 += rs[lane];
        if (lane < IN_DIM-64) a1 += rs[64+lane];
        s = snext;
      }
      float sc = rsqrtf((float)num + 1.f);
      a0 *= sc; a1 *= sc;
    }
    rowsT[lane][nn] = a0;
    if (lane < IN_DIM-64) rowsT[64+lane][nn] = a1;
  }
  __syncthreads();

  // GEMM: thread (c, rh) computes 8 nodes x channel c
  int c = tid & 127, rh = tid >> 7;
  float acc[8];
  #pragma unroll
  for (int i = 0; i < 8; ++i) acc[i] = 0.f;
  for (int k = 0; k < IN_DIM; ++k){
    float w = Wl[k*HID + c];
    const float4* rp = (const float4*)&rowsT[k][rh*8];
    float4 r0 = rp[0], r1 = rp[1];
    acc[0] += r0.x*w; acc[1] += r0.y*w; acc[2] += r0.z*w; acc[3] += r0.w*w;
    acc[4] += r1.x*w; acc[5] += r1.y*w; acc[6] += r1.z*w; acc[7] += r1.w*w;
  }
  float bv = bias[c];
  float run = 0.f;
  int curg = lgid[rh*8];
  #pragma unroll
  for (int i = 0; i < 8; ++i){
    int node = rh*8 + i;
    if (base + node >= N) break;
    int g = lgid[node];
    if (g != curg){
      if (run != 0.f) atomicAdd(&S[(size_t)curg*HID + c], run);
      run = 0.f; curg = g;
    }
    run += fmaxf(acc[i] + bv, 0.f);
  }
  if (run != 0.f) atomicAdd(&S[(size_t)curg*HID + c], run);
}

__global__ __launch_bounds__(128) void k_graph_tail(const float* __restrict__ S,
    const int* __restrict__ gid,
    const float* __restrict__ W_ri, const float* __restrict__ b_ri,
    const float* __restrict__ W_ro, const float* __restrict__ b_ro,
    const float* __restrict__ Wc1, const float* __restrict__ bc1,
    const float* __restrict__ Wc2, const float* __restrict__ bc2,
    float* __restrict__ z, int N){
  __shared__ float va[128], vb[128];
  __shared__ int bounds[2];
  int g = blockIdx.x, c = threadIdx.x;
  if (c < 2){
    int target = g + c, lo = 0, hi = N;
    while (lo < hi){ int mid = (lo+hi)>>1; if (gid[mid] < target) lo = mid+1; else hi = mid; }
    bounds[c] = lo;
  }
  __syncthreads();
  float cn = (float)(bounds[1] - bounds[0]);
  va[c] = S[(size_t)g*HID + c];
  __syncthreads();
  float s = 0.f;
  for (int k = 0; k < 128; ++k) s += va[k]*W_ri[k*128 + c];
  vb[c] = s + b_ri[c]*cn;
  __syncthreads();
  s = 0.f;
  for (int k = 0; k < 128; ++k) s += vb[k]*W_ro[k*128 + c];
  va[c] = fmaxf(s + b_ro[c]*cn, 0.f);
  __syncthreads();
  s = 0.f;
  for (int k = 0; k < 128; ++k) s += va[k]*Wc1[k*128 + c];
  vb[c] = fmaxf(s + bc1[c], 0.f);
  __syncthreads();
  s = 0.f;
  for (int k = 0; k < 128; ++k) s += vb[k]*Wc2[k*128 + c];
  z[(size_t)g*256 + c] = fmaxf(s + bc2[c], 0.f);
}

// ---------- fused setup ----------
__global__ void k_setup(const float* __restrict__ K1, const float* __restrict__ K2,
                        const float* __restrict__ K3, const float* __restrict__ K4,
                        const float* __restrict__ cb1, const float* __restrict__ cb2,
                        const float* __restrict__ cb3, const float* __restrict__ cb4,
                        u16* __restrict__ AW, float* __restrict__ ball,
                        float* __restrict__ z, float* __restrict__ S,
                        int* __restrict__ out_cnt, int* __restrict__ in_cnt,
                        int N, int B){
  int idx = blockIdx.x*256 + threadIdx.x;
  if (idx < NCHUNK*4096){
    int g = idx >> 12, rem = idx & 4095;
    int co = rem >> 5, kk = rem & 31;
    const float* Kw; int CIN, CPAD, COUT, ksl;
    if (g < 12)      { Kw = K1; CIN = 128; CPAD = 128; COUT =  96; ksl = g; }
    else if (g < 21) { Kw = K2; CIN =  96; CPAD =  96; COUT = 128; ksl = g-12; }
    else if (g < 33) { Kw = K3; CIN =  74; CPAD = 128; COUT =  74; ksl = g-21; }
    else             { Kw = K4; CIN =  74; CPAD =  96; COUT = 128; ksl = g-33; }
    int k = ksl*32 + kk;
    int t = k / CPAD, ci = k - t*CPAD;
    float v = (co < COUT && ci < CIN) ? Kw[((size_t)co*CIN + ci)*3 + t] : 0.f;
    int sl2 = (kk >> 3) ^ ((co >> 1) & 3);            // A-read swizzle
    AW[(size_t)g*4096 + co*32 + sl2*8 + (kk & 7)] = f2bf(v);
    return;
  }
  idx -= NCHUNK*4096;
  if (idx < 448){
    float v = 0.f;
    if (idx < 96) v = cb1[idx];
    else if (idx < 224) v = cb2[idx-96];
    else if (idx < 320){ int c = idx-224; v = (c < 74) ? cb3[c] : 0.f; }
    else v = cb4[idx-320];
    ball[idx] = v;
    return;
  }
  idx -= 448;
  if (idx < B*128){ z[(size_t)(idx>>7)*256 + 128 + (idx&127)] = 0.f; return; }
  idx -= B*128;
  if (idx < B*128){ S[idx] = 0.f; return; }
  idx -= B*128;
  if (idx < 2*N){
    if (idx < N) out_cnt[idx] = 0; else in_cnt[idx-N] = 0;
  }
}

// ---------- protein fused kernel (r12/r13 measured-best, unchanged) ----------
__device__ __forceinline__ void stage24k(char* lds, int tid, const u16* src, int pbuf){
  const char* s = (const char*)src;
  char* d = lds + pbuf*WBUF_SZ;
  #pragma unroll
  for (int i = 0; i < 3; ++i)
    __builtin_amdgcn_global_load_lds(
      (const __attribute__((address_space(1))) unsigned*)(s + i*8192 + tid*16),
      (__attribute__((address_space(3))) unsigned*)(d + i*8192 + tid*16), 16, 0, 0);
}

template<int KS, int G0, int M, int TPC, int RS_IN, int RCAP>
__device__ __forceinline__ void conv_phases(char* lds, const char* actIn,
    const u16* __restrict__ AW, int co0, int lm, int cg, int scg, int tid,
    f32x4 (&acc)[M][4])
{
  #pragma unroll
  for (int m = 0; m < M; ++m)
    #pragma unroll
    for (int n = 0; n < 4; ++n) acc[m][n] = (f32x4){0.f,0.f,0.f,0.f};
  #pragma unroll
  for (int ks = 0; ks < KS; ++ks){
    const int g = G0 + ks;
    const char* wb = lds + ((g/3)&1)*WBUF_SZ + (g%3)*8192;
    bf16x8 Af[M];
    #pragma unroll
    for (int m = 0; m < M; ++m)
      Af[m] = *(const bf16x8*)(wb + (co0 + m*16 + lm)*64 + scg*16);   // swizzled
    const int tap = ks / TPC;
    const int c16 = (ks - tap*TPC)*4 + cg;
    bf16x8 Bf[4];
    #pragma unroll
    for (int n = 0; n < 4; ++n){
      int raw = n*16 + lm + tap;
      int row = raw < RCAP ? raw : RCAP;      // clamp fires only for masked-out lanes
      Bf[n] = *(const bf16x8*)(actIn + row*RS_IN + c16*16);
    }
    __builtin_amdgcn_s_setprio(1);
    #pragma unroll
    for (int m = 0; m < M; ++m)
      #pragma unroll
      for (int n = 0; n < 4; ++n)
        acc[m][n] = __builtin_amdgcn_mfma_f32_16x16x32_bf16(Af[m], Bf[n], acc[m][n], 0, 0, 0);
    __builtin_amdgcn_s_setprio(0);
    if ((g % 3) == 2 && (ks + 1 < KS)){       // interior group boundary
      __syncthreads();
      const int gn = g/3 + 2;
      if (gn < NGRP) stage24k(lds, tid, AW + (size_t)gn*12288, gn & 1);
    }
  }
}

template<int M>
__device__ __forceinline__ void epi_store(char* actOut, int RS_OUT,
    const float* lbias, int boff, int co0, int lm, int cg,
    int lbase, int nrows, f32x4 (&acc)[M][4])
{
  #pragma unroll
  for (int m = 0; m < M; ++m){
    int co = co0 + m*16 + cg*4;
    float4 bb = *(const float4*)(lbias + boff + co);
    #pragma unroll
    for (int n = 0; n < 4; ++n){
      int r1 = n*16 + lm;
      if (r1 < nrows){
        int l = lbase + r1;
        u32 lo = 0, hi = 0;
        if ((unsigned)l < (unsigned)LSEQ){
          f32x4 a = acc[m][n];
          lo = pack2(fmaxf(a[0]+bb.x, 0.f), fmaxf(a[1]+bb.y, 0.f));
          hi = pack2(fmaxf(a[2]+bb.z, 0.f), fmaxf(a[3]+bb.w, 0.f));
        }
        uint2 st; st.x = lo; st.y = hi;
        *(uint2*)(actOut + r1*RS_OUT + co*2) = st;
      }
    }
  }
}

__device__ __forceinline__ void epi_pool(const float* lbias, int boff,
    int co0, int lm, int cg, int l0, float* __restrict__ z, int b, f32x4 (&acc)[4][4])
{
  float mxv[4][4];
  #pragma unroll
  for (int m = 0; m < 4; ++m)
    #pragma unroll
    for (int j = 0; j < 4; ++j) mxv[m][j] = 0.f;
  #pragma unroll
  for (int m = 0; m < 4; ++m){
    float4 bb = *(const float4*)(lbias + boff + co0 + m*16 + cg*4);
    const float* bv = (const float*)&bb;
    #pragma unroll
    for (int n = 0; n < 4; ++n){
      int r1 = n*16 + lm;
      int l = l0 + r1;
      if (r1 < TILE && l < LSEQ){
        #pragma unroll
        for (int j = 0; j < 4; ++j)
          mxv[m][j] = fmaxf(mxv[m][j], fmaxf(acc[m][n][j] + bv[j], 0.f));
      }
    }
  }
  #pragma unroll
  for (int o = 1; o <= 8; o <<= 1)
    #pragma unroll
    for (int m = 0; m < 4; ++m)
      #pragma unroll
      for (int j = 0; j < 4; ++j)
        mxv[m][j] = fmaxf(mxv[m][j], __shfl_xor(mxv[m][j], o));
  if (lm == 0){
    float* zrow = z + (size_t)b*256 + 128;
    #pragma unroll
    for (int m = 0; m < 4; ++m)
      #pragma unroll
      for (int j = 0; j < 4; ++j)
        atomicMax((u32*)(zrow + co0 + m*16 + cg*4 + j), __float_as_uint(mxv[m][j]));
  }
}

__global__ __launch_bounds__(512, 1) void k_protein(
    const int* __restrict__ seq, const float* __restrict__ emb,
    const u16* __restrict__ AW, const float* __restrict__ ball,
    float* __restrict__ z)
{
  __shared__ __align__(16) char lds[LDS_TOTAL];
  const int tid = threadIdx.x;
  const int lane = tid & 63, wid = tid >> 6;
  const int lm = lane & 15, cg = lane >> 4;
  const int scg = cg ^ ((lm >> 1) & 3);      // A-read swizzle slot
  const int tl = wid >> 1;                   // tile 0..3
  const int h  = wid & 1;                    // co-half
  const int b  = blockIdx.y;
  const int l0 = (blockIdx.x*4 + tl) * TILE;

  for (int i = tid; i < 448; i += 512) ((float*)(lds + LDS_BIAS))[i] = ball[i];

  for (int idx = tid; idx < 4*R0*16; idx += 512){
    int t2 = idx / (R0*16), rem = idx - t2*(R0*16);
    int r = rem >> 4, p = rem & 15;
    int ll0 = (blockIdx.x*4 + t2) * TILE;
    int l = ll0 - 4 + r;
    uint4 st = make_uint4(0u,0u,0u,0u);
    if ((unsigned)l < (unsigned)LSEQ){
      int tok = seq[b*LSEQ + l];
      const float4* e = (const float4*)(emb + (size_t)tok*HID + p*8);
      float4 v0 = e[0], v1 = e[1];
      st.x = pack2(v0.x, v0.y); st.y = pack2(v0.z, v0.w);
      st.z = pack2(v1.x, v1.y); st.w = pack2(v1.z, v1.w);
    }
    *(uint4*)(lds + LDS_ACT + t2*ACTA_SZ + r*RSA + p*16) = st;
  }
  stage24k(lds, tid, AW, 0);                  // group 0
  stage24k(lds, tid, AW + 12288, 1);          // group 1
  __syncthreads();

  char* actA = lds + LDS_ACT + tl*ACTA_SZ;
  char* actB = lds + ACTB_BASE + tl*ACTB_SZ;
  const float* lbias = (const float*)(lds + LDS_BIAS);

  { // L1: 128 -> 96 (chunks 0-11, groups 0-3)
    f32x4 acc[3][4];
    conv_phases<12,0,3,4,RSA,R0-1>(lds, actA, AW, h*48, lm, cg, scg, tid, acc);
    epi_store<3>(actB, RSB, lbias, 0, h*48, lm, cg, l0-3, R1, acc);
    __syncthreads();
    stage24k(lds, tid, AW + (size_t)5*12288, 5 & 1);      // group 5
  }
  { // L2: 96 -> 128 (chunks 12-20, groups 4-6)
    f32x4 acc[4][4];
    conv_phases<9,12,4,3,RSB,R1-1>(lds, actB, AW, h*64, lm, cg, scg, tid, acc);
    epi_store<4>(actA, RSA, lbias, 96, h*64, lm, cg, l0-2, R2, acc);
    __syncthreads();
    stage24k(lds, tid, AW + (size_t)8*12288, 8 & 1);      // group 8
  }
  { // L3: 128 -> 96 (chunks 21-32, groups 7-10)
    f32x4 acc[3][4];
    conv_phases<12,21,3,4,RSA,R2-1>(lds, actA, AW, h*48, lm, cg, scg, tid, acc);
    epi_store<3>(actB, RSB, lbias, 224, h*48, lm, cg, l0-1, R3, acc);
    __syncthreads();
    stage24k(lds, tid, AW + (size_t)12*12288, 12 & 1);    // group 12
  }
  { // L4: 96 -> 128 + maxpool (chunks 33-41, groups 11-13)
    f32x4 acc[4][4];
    conv_phases<9,33,4,3,RSB,R3-1>(lds, actB, AW, h*64, lm, cg, scg, tid, acc);
    epi_pool(lbias, 320, h*64, lm, cg, l0, z, b, acc);
  }
}

// head
__global__ __launch_bounds__(256) void k_fc_head(const float* __restrict__ z,
    const float* __restrict__ Wf1, const float* __restrict__ bf1,
    const float* __restrict__ Wf2, const float* __restrict__ bf2v,
    float* __restrict__ out){
  __shared__ float za[256];
  __shared__ float red[4];
  int r = blockIdx.x, c = threadIdx.x;
  za[c] = z[(size_t)r*256 + c];
  __syncthreads();
  float s = 0.f;
  for (int k = 0; k < 256; ++k) s += za[k]*Wf1[(size_t)k*256 + c];
  s = fmaxf(s + bf1[c], 0.f);
  float p = s * Wf2[c];
  for (int o = 32; o; o >>= 1) p += __shfl_xor(p, o);
  if ((c & 63) == 0) red[c >> 6] = p;
  __syncthreads();
  if (c == 0) out[r] = 1.f/(1.f + __expf(-(red[0]+red[1]+red[2]+red[3] + bf2v[0])));
}

extern "C" void kernel_launch(void* const* d_in, const int* in_sizes, int n_in,
                              void* d_out, int out_size, void* d_ws, size_t ws_size,
                              hipStream_t stream){
  const float* nf   = (const float*)d_in[0];
  const float* W_gc = (const float*)d_in[1];
  const float* b_gc = (const float*)d_in[2];
  const float* W_ri = (const float*)d_in[3];
  const float* b_ri = (const float*)d_in[4];
  const float* W_ro = (const float*)d_in[5];
  const float* b_ro = (const float*)d_in[6];
  const float* Wc1  = (const float*)d_in[7];
  const float* bc1  = (const float*)d_in[8];
  const float* Wc2  = (const float*)d_in[9];
  const float* bc2  = (const float*)d_in[10];
  const float* emb  = (const float*)d_in[11];
  const float* K1 = (const float*)d_in[12]; const float* cb1 = (const float*)d_in[13];
  const float* K2 = (const float*)d_in[14]; const float* cb2 = (const float*)d_in[15];
  const float* K3 = (const float*)d_in[16]; const float* cb3 = (const float*)d_in[17];
  const float* K4 = (const float*)d_in[18]; const float* cb4 = (const float*)d_in[19];
  const float* Wf1 = (const float*)d_in[20]; const float* bf1 = (const float*)d_in[21];
  const float* Wf2 = (const float*)d_in[22]; const float* bf2v = (const float*)d_in[23];
  const int* esrc = (const int*)d_in[24];
  const int* edst = (const int*)d_in[25];
  const int* gids = (const int*)d_in[26];
  const int* seq  = (const int*)d_in[27];
  float* out = (float*)d_out;

  int N = in_sizes[26];
  int E = in_sizes[24];
  int B = out_size;
  int nb = (N + 255)/256;

  char* ws = (char*)d_ws;
  size_t off = 0;
  auto take = [&](size_t bytes)->char*{
    char* p = ws + off; off = (off + bytes + 255) & ~(size_t)255; return p;
  };
  float* z      = (float*)take((size_t)B*2*HID*4);
  float* S      = (float*)take((size_t)B*HID*4);
  int* out_cnt  = (int*)take((size_t)N*4);
  int* in_cnt   = (int*)take((size_t)N*4);
  int* pref     = (int*)take((size_t)N*4);
  int* offs     = (int*)take((size_t)N*4);
  int* cur      = (int*)take((size_t)N*4);
  int* bsum     = (int*)take(1024*4);
  int* csr_src  = (int*)take((size_t)E*4);
  u16* AW       = (u16*)take((size_t)NCHUNK*8192);
  float* ball   = (float*)take(448*4);
  float* nfs    = (float*)take((size_t)N*IN_DIM*4);

  // ---- fused setup ----
  int setup_total = NCHUNK*4096 + 448 + B*128 + B*128 + 2*N;
  k_setup<<<(setup_total+255)/256, 256, 0, stream>>>(K1, K2, K3, K4, cb1, cb2, cb3, cb4,
                                                     AW, ball, z, S, out_cnt, in_cnt, N, B);

  // ---- graph branch ----
  k_cnt_edge<<<(E+255)/256, 256, 0, stream>>>(esrc, edst, out_cnt, in_cnt, E);
  k_nfs<<<((N*IN_DIM)+255)/256, 256, 0, stream>>>(nf, out_cnt, nfs, N*IN_DIM);
  k_scan1<<<nb, 256, 0, stream>>>(in_cnt, pref, bsum, N);
  k_scan2<<<1, 1024, 0, stream>>>(bsum, nb);
  k_scan3<<<nb, 256, 0, stream>>>(pref, bsum, offs, cur, N);
  k_csr_fill<<<(E+255)/256, 256, 0, stream>>>(esrc, edst, cur, csr_src, E);
  k_mega<<<(N+15)/16, 256, 0, stream>>>(nfs, csr_src, offs, in_cnt,
                                        W_gc, b_gc, gids, S, N);
  k_graph_tail<<<B, 128, 0, stream>>>(S, gids, W_ri, b_ri, W_ro, b_ro,
                                      Wc1, bc1, Wc2, bc2, z, N);

  // ---- protein branch: 5 x-blocks x 4 tiles of 50 (= exactly 1000) ----
  dim3 pgrid(5, B);
  k_protein<<<pgrid, 512, 0, stream>>>(seq, emb, AW, ball, z);

  // ---- head ----
  k_fc_head<<<B, 256, 0, stream>>>(z, Wf1, bf1, Wf2, bf2v, out);
}

// Round 16
// 407.681 us; speedup vs baseline: 1.9338x; 1.9338x over previous
//
#include <hip/hip_runtime.h>
#include <math.h>

#define IN_DIM 74
#define HID 128
#define LSEQ 1000
#define RSA 272      // 128-ch act LDS row bytes (17 x 16B)
#define RSB 208      // 96-ch act LDS row bytes (13 x 16B)
#define TILE 50
#define R0 58        // X0 rows, l = l0-4+r
#define R1 56        // X1 rows, l = l0-3+r
#define R2 54        // X2 rows, l = l0-2+r
#define R3 52        // X3 rows, l = l0-1+r
#define NCHUNK 42
#define NGRP 14
#define WBUF_SZ 24576
#define LDS_BIAS 49152
#define LDS_ACT  50944
#define ACTA_SZ  15776            // 58*272
#define ACTB_SZ  11648            // 56*208
#define ACTB_BASE (LDS_ACT + 4*ACTA_SZ)       // 114048
#define LDS_TOTAL (ACTB_BASE + 4*ACTB_SZ)     // 160640

typedef unsigned int u32;
typedef unsigned short u16;

typedef __attribute__((ext_vector_type(8))) short bf16x8;
typedef __attribute__((ext_vector_type(4))) float f32x4;

__device__ __forceinline__ u16 f2bf(float f){
  u32 u = __float_as_uint(f);
  u32 r = (u + 0x7fffu + ((u >> 16) & 1u)) >> 16;
  return (u16)r;
}
__device__ __forceinline__ u32 pack2(float x, float y){
  return (u32)f2bf(x) | ((u32)f2bf(y) << 16);
}

// ---------- graph branch ----------
__global__ void k_cnt_edge(const int* __restrict__ src, const int* __restrict__ dst,
                           int* out_cnt, int* in_cnt, int E){
  int e = blockIdx.x*256 + threadIdx.x;
  if (e < E){ atomicAdd(&out_cnt[src[e]], 1); atomicAdd(&in_cnt[dst[e]], 1); }
}
// nfs[i][f] = nf[i][f] * rsqrt(out_deg[i]+1)  (pre-scaled source rows)
__global__ void k_nfs(const float* __restrict__ nf, const int* __restrict__ out_cnt,
                      float* __restrict__ nfs, int total){
  int idx = blockIdx.x*256 + threadIdx.x;
  if (idx < total){
    int i = idx / IN_DIM;
    nfs[idx] = nf[idx] * rsqrtf((float)out_cnt[i] + 1.f);
  }
}
__global__ void k_scan1(const int* __restrict__ cnt, int* pref, int* bsum, int N){
  __shared__ int buf[256];
  int t = threadIdx.x, i = blockIdx.x*256 + t;
  int v = (i < N) ? cnt[i] : 0;
  buf[t] = v; __syncthreads();
  for (int o = 1; o < 256; o <<= 1){
    int tv = (t >= o) ? buf[t-o] : 0;
    __syncthreads(); buf[t] += tv; __syncthreads();
  }
  if (i < N) pref[i] = buf[t] - v;
  if (t == 255) bsum[blockIdx.x] = buf[255];
}
__global__ void k_scan2(int* bsum, int nb){
  __shared__ int buf[1024];
  int t = threadIdx.x;
  int v = (t < nb) ? bsum[t] : 0;
  buf[t] = v; __syncthreads();
  for (int o = 1; o < 1024; o <<= 1){
    int tv = (t >= o) ? buf[t-o] : 0;
    __syncthreads(); buf[t] += tv; __syncthreads();
  }
  if (t < nb) bsum[t] = buf[t] - v;
}
__global__ void k_scan3(const int* __restrict__ pref, const int* __restrict__ bsum,
                        int* offs, int* cur, int N){
  int i = blockIdx.x*256 + threadIdx.x;
  if (i < N){ int o = pref[i] + bsum[blockIdx.x]; offs[i] = o; cur[i] = o; }
}
__global__ void k_csr_fill(const int* __restrict__ src, const int* __restrict__ dst,
                           int* cur, int* csr_src, int E){
  int e = blockIdx.x*256 + threadIdx.x;
  if (e < E){ int slot = atomicAdd(&cur[dst[e]], 1); csr_src[slot] = src[e]; }
}

// fused: CSR gather (pre-scaled rows) + GraphConv GEMM + bias + ReLU + segment sum -> S
// r13-measured structure: 32 nodes/block.
__global__ __launch_bounds__(256) void k_mega(const float* __restrict__ nfs,
    const int* __restrict__ csr_src, const int* __restrict__ offs,
    const int* __restrict__ in_cnt,
    const float* __restrict__ W, const float* __restrict__ bias,
    const int* __restrict__ gid, float* __restrict__ S, int N){
  __shared__ float Wl[IN_DIM*HID];
  __shared__ float rowsT[IN_DIM][36];
  __shared__ int lgid[32];
  const int tid = threadIdx.x;
  const int base = blockIdx.x * 32;
  for (int i = tid; i < IN_DIM*HID; i += 256) Wl[i] = W[i];
  if (tid < 32) lgid[tid] = (base + tid < N) ? gid[base + tid] : 0;

  int wid = tid >> 6, lane = tid & 63;
  for (int nn = wid; nn < 32; nn += 4){
    int d = base + nn;
    float a0 = 0.f, a1 = 0.f;
    if (d < N){
      int beg = offs[d], num = in_cnt[d];
      const float* row = nfs + (size_t)d*IN_DIM;
      a0 = row[lane];
      if (lane < IN_DIM-64) a1 = row[64+lane];
      for (int j = 0; j < num; ++j){
        int s = csr_src[beg + j];
        const float* rs = nfs + (size_t)s*IN_DIM;
        a0 += rs[lane];
        if (lane < IN_DIM-64) a1 += rs[64+lane];
      }
      float sc = rsqrtf((float)num + 1.f);
      a0 *= sc; a1 *= sc;
    }
    rowsT[lane][nn] = a0;
    if (lane < IN_DIM-64) rowsT[64+lane][nn] = a1;
  }
  __syncthreads();

  int c = tid & 127, rh = tid >> 7;
  float acc[16];
  #pragma unroll
  for (int i = 0; i < 16; ++i) acc[i] = 0.f;
  for (int k = 0; k < IN_DIM; ++k){
    float w = Wl[k*HID + c];
    const float4* rp = (const float4*)&rowsT[k][rh*16];
    float4 r0 = rp[0], r1 = rp[1], r2 = rp[2], r3 = rp[3];
    acc[0] += r0.x*w; acc[1] += r0.y*w; acc[2] += r0.z*w; acc[3] += r0.w*w;
    acc[4] += r1.x*w; acc[5] += r1.y*w; acc[6] += r1.z*w; acc[7] += r1.w*w;
    acc[8] += r2.x*w; acc[9] += r2.y*w; acc[10] += r2.z*w; acc[11] += r2.w*w;
    acc[12] += r3.x*w; acc[13] += r3.y*w; acc[14] += r3.z*w; acc[15] += r3.w*w;
  }
  float bv = bias[c];
  float run = 0.f;
  int curg = lgid[rh*16];
  #pragma unroll
  for (int i = 0; i < 16; ++i){
    int node = rh*16 + i;
    if (base + node >= N) break;
    int g = lgid[node];
    if (g != curg){
      if (run != 0.f) atomicAdd(&S[(size_t)curg*HID + c], run);
      run = 0.f; curg = g;
    }
    run += fmaxf(acc[i] + bv, 0.f);
  }
  if (run != 0.f) atomicAdd(&S[(size_t)curg*HID + c], run);
}

__global__ __launch_bounds__(128) void k_graph_tail(const float* __restrict__ S,
    const int* __restrict__ gid,
    const float* __restrict__ W_ri, const float* __restrict__ b_ri,
    const float* __restrict__ W_ro, const float* __restrict__ b_ro,
    const float* __restrict__ Wc1, const float* __restrict__ bc1,
    const float* __restrict__ Wc2, const float* __restrict__ bc2,
    float* __restrict__ z, int N){
  __shared__ float va[128], vb[128];
  __shared__ int bounds[2];
  int g = blockIdx.x, c = threadIdx.x;
  if (c < 2){
    int target = g + c, lo = 0, hi = N;
    while (lo < hi){ int mid = (lo+hi)>>1; if (gid[mid] < target) lo = mid+1; else hi = mid; }
    bounds[c] = lo;
  }
  __syncthreads();
  float cn = (float)(bounds[1] - bounds[0]);
  va[c] = S[(size_t)g*HID + c];
  __syncthreads();
  float s = 0.f;
  for (int k = 0; k < 128; ++k) s += va[k]*W_ri[k*128 + c];
  vb[c] = s + b_ri[c]*cn;
  __syncthreads();
  s = 0.f;
  for (int k = 0; k < 128; ++k) s += vb[k]*W_ro[k*128 + c];
  va[c] = fmaxf(s + b_ro[c]*cn, 0.f);
  __syncthreads();
  s = 0.f;
  for (int k = 0; k < 128; ++k) s += va[k]*Wc1[k*128 + c];
  vb[c] = fmaxf(s + bc1[c], 0.f);
  __syncthreads();
  s = 0.f;
  for (int k = 0; k < 128; ++k) s += vb[k]*Wc2[k*128 + c];
  z[(size_t)g*256 + c] = fmaxf(s + bc2[c], 0.f);
}

// ---------- fused setup ----------
__global__ void k_setup(const float* __restrict__ K1, const float* __restrict__ K2,
                        const float* __restrict__ K3, const float* __restrict__ K4,
                        const float* __restrict__ cb1, const float* __restrict__ cb2,
                        const float* __restrict__ cb3, const float* __restrict__ cb4,
                        u16* __restrict__ AW, float* __restrict__ ball,
                        float* __restrict__ z, float* __restrict__ S,
                        int* __restrict__ out_cnt, int* __restrict__ in_cnt,
                        int N, int B){
  int idx = blockIdx.x*256 + threadIdx.x;
  if (idx < NCHUNK*4096){
    int g = idx >> 12, rem = idx & 4095;
    int co = rem >> 5, kk = rem & 31;
    const float* Kw; int CIN, CPAD, COUT, ksl;
    if (g < 12)      { Kw = K1; CIN = 128; CPAD = 128; COUT =  96; ksl = g; }
    else if (g < 21) { Kw = K2; CIN =  96; CPAD =  96; COUT = 128; ksl = g-12; }
    else if (g < 33) { Kw = K3; CIN =  74; CPAD = 128; COUT =  74; ksl = g-21; }
    else             { Kw = K4; CIN =  74; CPAD =  96; COUT = 128; ksl = g-33; }
    int k = ksl*32 + kk;
    int t = k / CPAD, ci = k - t*CPAD;
    float v = (co < COUT && ci < CIN) ? Kw[((size_t)co*CIN + ci)*3 + t] : 0.f;
    int sl2 = (kk >> 3) ^ ((co >> 1) & 3);            // A-read swizzle
    AW[(size_t)g*4096 + co*32 + sl2*8 + (kk & 7)] = f2bf(v);
    return;
  }
  idx -= NCHUNK*4096;
  if (idx < 448){
    float v = 0.f;
    if (idx < 96) v = cb1[idx];
    else if (idx < 224) v = cb2[idx-96];
    else if (idx < 320){ int c = idx-224; v = (c < 74) ? cb3[c] : 0.f; }
    else v = cb4[idx-320];
    ball[idx] = v;
    return;
  }
  idx -= 448;
  if (idx < B*128){ z[(size_t)(idx>>7)*256 + 128 + (idx&127)] = 0.f; return; }
  idx -= B*128;
  if (idx < B*128){ S[idx] = 0.f; return; }
  idx -= B*128;
  if (idx < 2*N){
    if (idx < N) out_cnt[idx] = 0; else in_cnt[idx-N] = 0;
  }
}

// ---------- protein fused kernel (r12/r13 measured-best, unchanged) ----------
__device__ __forceinline__ void stage24k(char* lds, int tid, const u16* src, int pbuf){
  const char* s = (const char*)src;
  char* d = lds + pbuf*WBUF_SZ;
  #pragma unroll
  for (int i = 0; i < 3; ++i)
    __builtin_amdgcn_global_load_lds(
      (const __attribute__((address_space(1))) unsigned*)(s + i*8192 + tid*16),
      (__attribute__((address_space(3))) unsigned*)(d + i*8192 + tid*16), 16, 0, 0);
}

template<int KS, int G0, int M, int TPC, int RS_IN, int RCAP>
__device__ __forceinline__ void conv_phases(char* lds, const char* actIn,
    const u16* __restrict__ AW, int co0, int lm, int cg, int scg, int tid,
    f32x4 (&acc)[M][4])
{
  #pragma unroll
  for (int m = 0; m < M; ++m)
    #pragma unroll
    for (int n = 0; n < 4; ++n) acc[m][n] = (f32x4){0.f,0.f,0.f,0.f};
  #pragma unroll
  for (int ks = 0; ks < KS; ++ks){
    const int g = G0 + ks;
    const char* wb = lds + ((g/3)&1)*WBUF_SZ + (g%3)*8192;
    bf16x8 Af[M];
    #pragma unroll
    for (int m = 0; m < M; ++m)
      Af[m] = *(const bf16x8*)(wb + (co0 + m*16 + lm)*64 + scg*16);   // swizzled
    const int tap = ks / TPC;
    const int c16 = (ks - tap*TPC)*4 + cg;
    bf16x8 Bf[4];
    #pragma unroll
    for (int n = 0; n < 4; ++n){
      int raw = n*16 + lm + tap;
      int row = raw < RCAP ? raw : RCAP;      // clamp fires only for masked-out lanes
      Bf[n] = *(const bf16x8*)(actIn + row*RS_IN + c16*16);
    }
    __builtin_amdgcn_s_setprio(1);
    #pragma unroll
    for (int m = 0; m < M; ++m)
      #pragma unroll
      for (int n = 0; n < 4; ++n)
        acc[m][n] = __builtin_amdgcn_mfma_f32_16x16x32_bf16(Af[m], Bf[n], acc[m][n], 0, 0, 0);
    __builtin_amdgcn_s_setprio(0);
    if ((g % 3) == 2 && (ks + 1 < KS)){       // interior group boundary
      __syncthreads();
      const int gn = g/3 + 2;
      if (gn < NGRP) stage24k(lds, tid, AW + (size_t)gn*12288, gn & 1);
    }
  }
}

template<int M>
__device__ __forceinline__ void epi_store(char* actOut, int RS_OUT,
    const float* lbias, int boff, int co0, int lm, int cg,
    int lbase, int nrows, f32x4 (&acc)[M][4])
{
  #pragma unroll
  for (int m = 0; m < M; ++m){
    int co = co0 + m*16 + cg*4;
    float4 bb = *(const float4*)(lbias + boff + co);
    #pragma unroll
    for (int n = 0; n < 4; ++n){
      int r1 = n*16 + lm;
      if (r1 < nrows){
        int l = lbase + r1;
        u32 lo = 0, hi = 0;
        if ((unsigned)l < (unsigned)LSEQ){
          f32x4 a = acc[m][n];
          lo = pack2(fmaxf(a[0]+bb.x, 0.f), fmaxf(a[1]+bb.y, 0.f));
          hi = pack2(fmaxf(a[2]+bb.z, 0.f), fmaxf(a[3]+bb.w, 0.f));
        }
        uint2 st; st.x = lo; st.y = hi;
        *(uint2*)(actOut + r1*RS_OUT + co*2) = st;
      }
    }
  }
}

__device__ __forceinline__ void epi_pool(const float* lbias, int boff,
    int co0, int lm, int cg, int l0, float* __restrict__ z, int b, f32x4 (&acc)[4][4])
{
  float mxv[4][4];
  #pragma unroll
  for (int m = 0; m < 4; ++m)
    #pragma unroll
    for (int j = 0; j < 4; ++j) mxv[m][j] = 0.f;
  #pragma unroll
  for (int m = 0; m < 4; ++m){
    float4 bb = *(const float4*)(lbias + boff + co0 + m*16 + cg*4);
    const float* bv = (const float*)&bb;
    #pragma unroll
    for (int n = 0; n < 4; ++n){
      int r1 = n*16 + lm;
      int l = l0 + r1;
      if (r1 < TILE && l < LSEQ){
        #pragma unroll
        for (int j = 0; j < 4; ++j)
          mxv[m][j] = fmaxf(mxv[m][j], fmaxf(acc[m][n][j] + bv[j], 0.f));
      }
    }
  }
  #pragma unroll
  for (int o = 1; o <= 8; o <<= 1)
    #pragma unroll
    for (int m = 0; m < 4; ++m)
      #pragma unroll
      for (int j = 0; j < 4; ++j)
        mxv[m][j] = fmaxf(mxv[m][j], __shfl_xor(mxv[m][j], o));
  if (lm == 0){
    float* zrow = z + (size_t)b*256 + 128;
    #pragma unroll
    for (int m = 0; m < 4; ++m)
      #pragma unroll
      for (int j = 0; j < 4; ++j)
        atomicMax((u32*)(zrow + co0 + m*16 + cg*4 + j), __float_as_uint(mxv[m][j]));
  }
}

__global__ __launch_bounds__(512, 1) void k_protein(
    const int* __restrict__ seq, const float* __restrict__ emb,
    const u16* __restrict__ AW, const float* __restrict__ ball,
    float* __restrict__ z)
{
  __shared__ __align__(16) char lds[LDS_TOTAL];
  const int tid = threadIdx.x;
  const int lane = tid & 63, wid = tid >> 6;
  const int lm = lane & 15, cg = lane >> 4;
  const int scg = cg ^ ((lm >> 1) & 3);      // A-read swizzle slot
  const int tl = wid >> 1;                   // tile 0..3
  const int h  = wid & 1;                    // co-half
  const int b  = blockIdx.y;
  const int l0 = (blockIdx.x*4 + tl) * TILE;

  for (int i = tid; i < 448; i += 512) ((float*)(lds + LDS_BIAS))[i] = ball[i];

  for (int idx = tid; idx < 4*R0*16; idx += 512){
    int t2 = idx / (R0*16), rem = idx - t2*(R0*16);
    int r = rem >> 4, p = rem & 15;
    int ll0 = (blockIdx.x*4 + t2) * TILE;
    int l = ll0 - 4 + r;
    uint4 st = make_uint4(0u,0u,0u,0u);
    if ((unsigned)l < (unsigned)LSEQ){
      int tok = seq[b*LSEQ + l];
      const float4* e = (const float4*)(emb + (size_t)tok*HID + p*8);
      float4 v0 = e[0], v1 = e[1];
      st.x = pack2(v0.x, v0.y); st.y = pack2(v0.z, v0.w);
      st.z = pack2(v1.x, v1.y); st.w = pack2(v1.z, v1.w);
    }
    *(uint4*)(lds + LDS_ACT + t2*ACTA_SZ + r*RSA + p*16) = st;
  }
  stage24k(lds, tid, AW, 0);                  // group 0
  stage24k(lds, tid, AW + 12288, 1);          // group 1
  __syncthreads();

  char* actA = lds + LDS_ACT + tl*ACTA_SZ;
  char* actB = lds + ACTB_BASE + tl*ACTB_SZ;
  const float* lbias = (const float*)(lds + LDS_BIAS);

  { // L1: 128 -> 96 (chunks 0-11, groups 0-3)
    f32x4 acc[3][4];
    conv_phases<12,0,3,4,RSA,R0-1>(lds, actA, AW, h*48, lm, cg, scg, tid, acc);
    epi_store<3>(actB, RSB, lbias, 0, h*48, lm, cg, l0-3, R1, acc);
    __syncthreads();
    stage24k(lds, tid, AW + (size_t)5*12288, 5 & 1);      // group 5
  }
  { // L2: 96 -> 128 (chunks 12-20, groups 4-6)
    f32x4 acc[4][4];
    conv_phases<9,12,4,3,RSB,R1-1>(lds, actB, AW, h*64, lm, cg, scg, tid, acc);
    epi_store<4>(actA, RSA, lbias, 96, h*64, lm, cg, l0-2, R2, acc);
    __syncthreads();
    stage24k(lds, tid, AW + (size_t)8*12288, 8 & 1);      // group 8
  }
  { // L3: 128 -> 96 (chunks 21-32, groups 7-10)
    f32x4 acc[3][4];
    conv_phases<12,21,3,4,RSA,R2-1>(lds, actA, AW, h*48, lm, cg, scg, tid, acc);
    epi_store<3>(actB, RSB, lbias, 224, h*48, lm, cg, l0-1, R3, acc);
    __syncthreads();
    stage24k(lds, tid, AW + (size_t)12*12288, 12 & 1);    // group 12
  }
  { // L4: 96 -> 128 + maxpool (chunks 33-41, groups 11-13)
    f32x4 acc[4][4];
    conv_phases<9,33,4,3,RSB,R3-1>(lds, actB, AW, h*64, lm, cg, scg, tid, acc);
    epi_pool(lbias, 320, h*64, lm, cg, l0, z, b, acc);
  }
}

// head
__global__ __launch_bounds__(256) void k_fc_head(const float* __restrict__ z,
    const float* __restrict__ Wf1, const float* __restrict__ bf1,
    const float* __restrict__ Wf2, const float* __restrict__ bf2v,
    float* __restrict__ out){
  __shared__ float za[256];
  __shared__ float red[4];
  int r = blockIdx.x, c = threadIdx.x;
  za[c] = z[(size_t)r*256 + c];
  __syncthreads();
  float s = 0.f;
  for (int k = 0; k < 256; ++k) s += za[k]*Wf1[(size_t)k*256 + c];
  s = fmaxf(s + bf1[c], 0.f);
  float p = s * Wf2[c];
  for (int o = 32; o; o >>= 1) p += __shfl_xor(p, o);
  if ((c & 63) == 0) red[c >> 6] = p;
  __syncthreads();
  if (c == 0) out[r] = 1.f/(1.f + __expf(-(red[0]+red[1]+red[2]+red[3] + bf2v[0])));
}

extern "C" void kernel_launch(void* const* d_in, const int* in_sizes, int n_in,
                              void* d_out, int out_size, void* d_ws, size_t ws_size,
                              hipStream_t stream){
  const float* nf   = (const float*)d_in[0];
  const float* W_gc = (const float*)d_in[1];
  const float* b_gc = (const float*)d_in[2];
  const float* W_ri = (const float*)d_in[3];
  const float* b_ri = (const float*)d_in[4];
  const float* W_ro = (const float*)d_in[5];
  const float* b_ro = (const float*)d_in[6];
  const float* Wc1  = (const float*)d_in[7];
  const float* bc1  = (const float*)d_in[8];
  const float* Wc2  = (const float*)d_in[9];
  const float* bc2  = (const float*)d_in[10];
  const float* emb  = (const float*)d_in[11];
  const float* K1 = (const float*)d_in[12]; const float* cb1 = (const float*)d_in[13];
  const float* K2 = (const float*)d_in[14]; const float* cb2 = (const float*)d_in[15];
  const float* K3 = (const float*)d_in[16]; const float* cb3 = (const float*)d_in[17];
  const float* K4 = (const float*)d_in[18]; const float* cb4 = (const float*)d_in[19];
  const float* Wf1 = (const float*)d_in[20]; const float* bf1 = (const float*)d_in[21];
  const float* Wf2 = (const float*)d_in[22]; const float* bf2v = (const float*)d_in[23];
  const int* esrc = (const int*)d_in[24];
  const int* edst = (const int*)d_in[25];
  const int* gids = (const int*)d_in[26];
  const int* seq  = (const int*)d_in[27];
  float* out = (float*)d_out;

  int N = in_sizes[26];
  int E = in_sizes[24];
  int B = out_size;
  int nb = (N + 255)/256;

  char* ws = (char*)d_ws;
  size_t off = 0;
  auto take = [&](size_t bytes)->char*{
    char* p = ws + off; off = (off + bytes + 255) & ~(size_t)255; return p;
  };
  float* z      = (float*)take((size_t)B*2*HID*4);
  float* S      = (float*)take((size_t)B*HID*4);
  int* out_cnt  = (int*)take((size_t)N*4);
  int* in_cnt   = (int*)take((size_t)N*4);
  int* pref     = (int*)take((size_t)N*4);
  int* offs     = (int*)take((size_t)N*4);
  int* cur      = (int*)take((size_t)N*4);
  int* bsum     = (int*)take(1024*4);
  int* csr_src  = (int*)take((size_t)E*4);
  u16* AW       = (u16*)take((size_t)NCHUNK*8192);
  float* ball   = (float*)take(448*4);
  float* nfs    = (float*)take((size_t)N*IN_DIM*4);

  // ---- fused setup ----
  int setup_total = NCHUNK*4096 + 448 + B*128 + B*128 + 2*N;
  k_setup<<<(setup_total+255)/256, 256, 0, stream>>>(K1, K2, K3, K4, cb1, cb2, cb3, cb4,
                                                     AW, ball, z, S, out_cnt, in_cnt, N, B);

  // ---- graph branch ----
  k_cnt_edge<<<(E+255)/256, 256, 0, stream>>>(esrc, edst, out_cnt, in_cnt, E);
  k_nfs<<<((N*IN_DIM)+255)/256, 256, 0, stream>>>(nf, out_cnt, nfs, N*IN_DIM);
  k_scan1<<<nb, 256, 0, stream>>>(in_cnt, pref, bsum, N);
  k_scan2<<<1, 1024, 0, stream>>>(bsum, nb);
  k_scan3<<<nb, 256, 0, stream>>>(pref, bsum, offs, cur, N);
  k_csr_fill<<<(E+255)/256, 256, 0, stream>>>(esrc, edst, cur, csr_src, E);
  k_mega<<<(N+31)/32, 256, 0, stream>>>(nfs, csr_src, offs, in_cnt,
                                        W_gc, b_gc, gids, S, N);
  k_graph_tail<<<B, 128, 0, stream>>>(S, gids, W_ri, b_ri, W_ro, b_ro,
                                      Wc1, bc1, Wc2, bc2, z, N);

  // ---- protein branch: 5 x-blocks x 4 tiles of 50 (= exactly 1000) ----
  dim3 pgrid(5, B);
  k_protein<<<pgrid, 512, 0, stream>>>(seq, emb, AW, ball, z);

  // ---- head ----
  k_fc_head<<<B, 256, 0, stream>>>(z, Wf1, bf1, Wf2, bf2v, out);
}